// Round 18
// baseline (1901.394 us; speedup 1.0000x reference)
//
#include <hip/hip_runtime.h>
#include <hip/hip_bf16.h>
#include <hip/hip_cooperative_groups.h>

namespace cg = cooperative_groups;

#define NLVL 20
#define PN   5000
#define EPLE 40000
#define FDIM 128
#define HDIM 256
#define NTOT (NLVL * PN)
#define CAP  32
#define ROWS 32
#define NBLK ((PN + ROWS - 1) / ROWS)

#define STR_(x) #x
#define GLD(dst, ptr, IMM) \
  asm volatile("global_load_dwordx4 %0, %1, off offset:" STR_(IMM) : "=v"(dst) : "v"(ptr))
#define WAITVM(N) do { asm volatile("s_waitcnt vmcnt(" STR_(N) ")" ::: "memory"); \
                       __builtin_amdgcn_sched_barrier(0); } while (0)
#define LBAR() do { asm volatile("s_waitcnt lgkmcnt(0)\n\ts_barrier" ::: "memory"); \
                    __builtin_amdgcn_sched_barrier(0); } while (0)

typedef __attribute__((ext_vector_type(8))) short short8;
typedef __attribute__((ext_vector_type(4))) float f32x4;

__device__ __forceinline__ f32x4 mfma16(short8 a, short8 b, f32x4 c) {
  return __builtin_amdgcn_mfma_f32_16x16x32_bf16(a, b, c, 0, 0, 0);
}
__device__ __forceinline__ ushort f2b(float f) {
  union { float f; unsigned u; } v; v.f = f;
  unsigned r = v.u + 0x7FFFu + ((v.u >> 16) & 1u);   // RNE
  return (ushort)(r >> 16);
}
__device__ __forceinline__ uint2 packu2(f32x4 v) {
  union { uint2 u2; ushort s[4]; } p;
  p.s[0] = f2b(v[0]); p.s[1] = f2b(v[1]); p.s[2] = f2b(v[2]); p.s[3] = f2b(v[3]);
  return p.u2;
}
__device__ __forceinline__ void addbf4(f32x4& s, uint2 v) {
  s[0] += __uint_as_float(v.x << 16);
  s[1] += __uint_as_float(v.x & 0xFFFF0000u);
  s[2] += __uint_as_float(v.y << 16);
  s[3] += __uint_as_float(v.y & 0xFFFF0000u);
}
__device__ __forceinline__ f32x4 relu4(f32x4 a) {
  f32x4 o;
  o[0] = fmaxf(a[0], 0.f); o[1] = fmaxf(a[1], 0.f);
  o[2] = fmaxf(a[2], 0.f); o[3] = fmaxf(a[3], 0.f);
  return o;
}

// ---- LDS act buffers: [32 rows][256 cols] bf16, XOR-swizzled ----
__device__ __forceinline__ void st_lds8(ushort* buf, int row, int byteoff, uint2 v) {
  *(uint2*)((char*)buf + row * 512 + (byteoff ^ ((row & 7) << 4))) = v;
}
__device__ __forceinline__ short8 ld_lds16(const ushort* buf, int row, int byteoff) {
  return *(const short8*)((const char*)buf + row * 512 + (byteoff ^ ((row & 7) << 4)));
}

// ---- fragment-major weights: chunk(ct, kc) = 1KB of lane-ordered short8 ----
__device__ __forceinline__ void ldw_asm(const ushort* __restrict__ Wm, int ctstride,
                                        short8* W, int cc0, int lane) {
  const ushort* pa = Wm + (size_t)cc0 * ctstride + lane * 8;
  const ushort* pb = pa + ctstride;
  GLD(W[0],  pa, 0);        GLD(W[1],  pa, 1024);
  GLD(W[2],  pa, 2048);     GLD(W[3],  pa, 3072);
  GLD(W[4],  pa + 2048, 0); GLD(W[5],  pa + 2048, 1024);
  GLD(W[6],  pa + 2048, 2048); GLD(W[7], pa + 2048, 3072);
  GLD(W[8],  pb, 0);        GLD(W[9],  pb, 1024);
  GLD(W[10], pb, 2048);     GLD(W[11], pb, 3072);
  GLD(W[12], pb + 2048, 0); GLD(W[13], pb + 2048, 1024);
  GLD(W[14], pb + 2048, 2048); GLD(W[15], pb + 2048, 3072);
}

__device__ __forceinline__ void rdBh(const ushort* buf, short8 B[2][4], int h, int r, int g) {
  #pragma unroll
  for (int rg = 0; rg < 2; ++rg)
    #pragma unroll
    for (int kc = 0; kc < 4; ++kc)
      B[rg][kc] = ld_lds16(buf, rg * 16 + r, 64 * (h * 4 + kc) + 16 * g);
}
__device__ __forceinline__ void mmhalf(const short8* W, short8 B[2][4],
                                       f32x4 acc[2][2], int h) {
  #pragma unroll
  for (int ct = 0; ct < 2; ++ct)
    #pragma unroll
    for (int rg = 0; rg < 2; ++rg)
      #pragma unroll
      for (int kc = 0; kc < 4; ++kc)
        acc[ct][rg] = mfma16(W[ct * 8 + h * 4 + kc], B[rg][kc], acc[ct][rg]);
}
__device__ __forceinline__ void stage_mm(const short8* W, const ushort* inbuf,
                                         const float* bias_s, int slot,
                                         f32x4 acc[2][2], int r, int g, int cc0) {
  #pragma unroll
  for (int ct = 0; ct < 2; ++ct) {
    f32x4 b = *(const f32x4*)(bias_s + slot * 256 + 16 * (cc0 + ct) + 4 * g);
    acc[ct][0] = b; acc[ct][1] = b;
  }
  short8 B[2][4];
  rdBh(inbuf, B, 0, r, g);
  mmhalf(W, B, acc, 0);
  rdBh(inbuf, B, 1, r, g);
  mmhalf(W, B, acc, 1);
}
__device__ __forceinline__ void relu_acc(f32x4 a[2][2]) {
  #pragma unroll
  for (int ct = 0; ct < 2; ++ct)
    #pragma unroll
    for (int rg = 0; rg < 2; ++rg) a[ct][rg] = relu4(a[ct][rg]);
}
__device__ __forceinline__ void wr_acc(ushort* buf, f32x4 a[2][2], int cc0, int r, int g) {
  #pragma unroll
  for (int ct = 0; ct < 2; ++ct)
    #pragma unroll
    for (int rg = 0; rg < 2; ++rg)
      st_lds8(buf, rg * 16 + r, 32 * (cc0 + ct) + 8 * g, packu2(a[ct][rg]));
}
__device__ __forceinline__ void wr_acc_add(ushort* buf, f32x4 a[2][2], f32x4 x[2][2],
                                           int cc0, int r, int g) {
  #pragma unroll
  for (int ct = 0; ct < 2; ++ct)
    #pragma unroll
    for (int rg = 0; rg < 2; ++rg)
      st_lds8(buf, rg * 16 + r, 32 * (cc0 + ct) + 8 * g, packu2(a[ct][rg] + x[ct][rg]));
}
__device__ __forceinline__ void cp_acc(f32x4 d[2][2], f32x4 s[2][2]) {
  #pragma unroll
  for (int ct = 0; ct < 2; ++ct)
    #pragma unroll
    for (int rg = 0; rg < 2; ++rg) d[ct][rg] = s[ct][rg];
}

// ---------------- CSR-lite build ----------------
__global__ void fill_csr_kernel(const int* __restrict__ esrc, const int* __restrict__ edst,
                                int* __restrict__ counts, int* __restrict__ buckets) {
  int e = blockIdx.x * 256 + threadIdx.x;
  if (e >= (NLVL - 1) * EPLE) return;
  int l = e / EPLE;
  int key = l * PN + edst[e];
  int pos = atomicAdd(&counts[key], 1);
  if (pos < CAP) buckets[(size_t)key * CAP + pos] = esrc[e];
}

// ------- weight prep: fp32 [K][N] row-major -> bf16 fragment-major chunks -------
__global__ void prep_w(const float* __restrict__ we, const float* __restrict__ mpw,
                       const float* __restrict__ nw0, const float* __restrict__ nww,
                       ushort* __restrict__ wef, ushort* __restrict__ mpf,
                       ushort* __restrict__ ne0f, ushort* __restrict__ nwf) {
  int i = blockIdx.x * 256 + threadIdx.x;
  if (i < 32768) {
    int e = i & 7, lane = (i >> 3) & 63, kc = (i >> 9) & 3, ct = i >> 11;
    int r = lane & 15, g = lane >> 4;
    int k = kc * 32 + 8 * g + e, n = 16 * ct + r;
    wef[i] = f2b(we[k * 256 + n]);
  }
  if (i < 4 * 65536) {
    int mi = i >> 16, o = i & 65535;
    int e = o & 7, lane = (o >> 3) & 63, kc = (o >> 9) & 7, ct = o >> 12;
    int r = lane & 15, g = lane >> 4;
    int k = kc * 32 + 8 * g + e, n = 16 * ct + r;
    mpf[i] = f2b(mpw[mi * 65536 + k * 256 + n]);
  }
  if (i < 131072) {
    int e = i & 7, lane = (i >> 3) & 63, kc = (i >> 9) & 15, ct = i >> 13;
    int r = lane & 15, g = lane >> 4;
    int k = kc * 32 + 8 * g + e, n = 16 * ct + r;
    ne0f[i] = f2b(nw0[k * 256 + n]);
  }
  if (i < 3 * 65536) {
    int mi = i >> 16, o = i & 65535;
    int e = o & 7, lane = (o >> 3) & 63, kc = (o >> 9) & 7, ct = o >> 12;
    int r = lane & 15, g = lane >> 4;
    int k = kc * 32 + 8 * g + e, n = 16 * ct + r;
    nwf[i] = f2b(nww[mi * 65536 + k * 256 + n]);
  }
}

// -------- embed for level-0 rows: 16 rows/block, 4 waves x 4 col-tiles --------
__global__ __launch_bounds__(256, 4) void embed0(
    const float* __restrict__ nf, const ushort* __restrict__ wef,
    const float* __restrict__ be, float* __restrict__ out,
    ushort* __restrict__ eb16) {
  const int w = threadIdx.x >> 6, lane = threadIdx.x & 63;
  const int r = lane & 15, g = lane >> 4;
  const int p = blockIdx.x * 16 + r;
  const int pc = p < PN ? p : PN - 1;

  short8 Bn[4];
  const float* nfr = nf + (size_t)pc * FDIM;
  #pragma unroll
  for (int kc = 0; kc < 4; ++kc) {
    f32x4 a0 = *(const f32x4*)(nfr + kc * 32 + 8 * g);
    f32x4 a1 = *(const f32x4*)(nfr + kc * 32 + 8 * g + 4);
    float t[8];
    t[0]=a0[0]; t[1]=a0[1]; t[2]=a0[2]; t[3]=a0[3];
    t[4]=a1[0]; t[5]=a1[1]; t[6]=a1[2]; t[7]=a1[3];
    short8 o;
    #pragma unroll
    for (int i = 0; i < 8; ++i) o[i] = (short)f2b(t[i]);
    Bn[kc] = o;
  }
  const int ct0 = 4 * w;
  #pragma unroll
  for (int t = 0; t < 4; ++t) {
    const int ct = ct0 + t;
    f32x4 acc = *(const f32x4*)(be + 16 * ct + 4 * g);
    #pragma unroll
    for (int kc = 0; kc < 4; ++kc)
      acc = mfma16(*(const short8*)(wef + (size_t)ct * 2048 + kc * 512 + lane * 8),
                   Bn[kc], acc);
    f32x4 o;
    o[0]=tanhf(acc[0]); o[1]=tanhf(acc[1]); o[2]=tanhf(acc[2]); o[3]=tanhf(acc[3]);
    if (p < PN) {
      *(f32x4*)(out + (size_t)p * HDIM + 16 * ct + 4 * g) = o;
      *(uint2*)(eb16 + (size_t)p * HDIM + 16 * ct + 4 * g) = packu2(o);
    }
  }
}

// ------- persistent cooperative level chain: 157 blocks, 19 levels in-kernel -------
__global__ __launch_bounds__(512, 2) void level_persist(
    float* __restrict__ eb, const float* __restrict__ nf,
    ushort* __restrict__ eb16,
    const int* __restrict__ counts, const int* __restrict__ buckets,
    const ushort* __restrict__ wef,
    const ushort* __restrict__ mpf, const ushort* __restrict__ ne0f,
    const ushort* __restrict__ nwf,
    const float* __restrict__ be, const float* __restrict__ mpb,
    const float* __restrict__ neb0, const float* __restrict__ neb) {
  __shared__ ushort Bs[4][ROWS * 256];
  __shared__ float bias_s[8 * 256];
  __shared__ int idx_s[ROWS * CAP];
  __shared__ int cnt_s[ROWS];
  const int tid = threadIdx.x, w = tid >> 6, lane = tid & 63;
  const int r = lane & 15, g = lane >> 4;
  const int p0 = blockIdx.x * ROWS;
  const int cc0 = 2 * w;
  cg::grid_group grid = cg::this_grid();

  short8 WA[16], WB[16], WE[8];
  f32x4 acc[2][2], X[2][2];

  // bias table staged ONCE (slots: 0..3 mp_b, 4 ne_b0, 5..7 ne_b)
  for (int i = tid; i < 2048; i += 512) {
    float v;
    if (i < 1024) v = mpb[i];
    else if (i < 1280) v = neb0[i - 1024];
    else v = neb[i - 1280];
    bias_s[i] = v;
  }

  for (int l = 0; l < NLVL - 1; ++l) {
    const int lP = l * PN;
    const ushort* ebA = eb16 + (size_t)(l & 1) * PN * HDIM;
    ushort* ebW = eb16 + (size_t)((l + 1) & 1) * PN * HDIM;

    // ---- stage bucket index table + counts (coalesced) ----
    {
      const int* gsrc = buckets + (size_t)(lP + p0) * CAP;
      for (int i = tid; i < ROWS * CAP; i += 512) idx_s[i] = gsrc[i];
      if (tid < ROWS) {
        int p = p0 + tid;
        cnt_s[tid] = (p < PN) ? min(counts[lP + p], CAP) : 0;
      }
    }
    // ---- issue embed + S1 weights (land under gather) ----
    {
      const ushort* pe0 = wef + (size_t)cc0 * 2048 + lane * 8;
      const ushort* pe1 = pe0 + 2048;
      GLD(WE[0], pe0, 0); GLD(WE[1], pe0, 1024); GLD(WE[2], pe0, 2048); GLD(WE[3], pe0, 3072);
      GLD(WE[4], pe1, 0); GLD(WE[5], pe1, 1024); GLD(WE[6], pe1, 2048); GLD(WE[7], pe1, 3072);
    }
    ldw_asm(mpf, 4096, WA, cc0, lane);
    LBAR();   // idx_s/cnt_s visible to all waves

    // ---- gather (4 rows/wave) via LDS indices -> Bs0 ----
    {
      const int qb = 4 * w;
      f32x4 s[4]; int cnt[4];
      #pragma unroll
      for (int i = 0; i < 4; ++i) {
        cnt[i] = cnt_s[qb + i];
        s[i][0]=0.f; s[i][1]=0.f; s[i][2]=0.f; s[i][3]=0.f;
      }
      int mx = max(max(cnt[0], cnt[1]), max(cnt[2], cnt[3]));
      for (int j = 0; j < mx; ++j) {
        #pragma unroll
        for (int i = 0; i < 4; ++i)
          if (j < cnt[i]) {
            int sl = idx_s[(qb + i) * CAP + j] - lP;
            addbf4(s[i], *(const uint2*)(ebA + (size_t)sl * HDIM + 4 * lane));
          }
      }
      #pragma unroll
      for (int i = 0; i < 4; ++i)
        st_lds8(Bs[0], qb + i, 8 * lane, packu2(s[i]));
    }

    // ---- fused embed: base = tanh(nf @ We + be) -> Bs3 ----
    {
      short8 Bn[2][4];
      #pragma unroll
      for (int rg = 0; rg < 2; ++rg) {
        int p = p0 + rg * 16 + r;
        const float* nfr = nf + (size_t)((l + 1) * PN + (p < PN ? p : PN - 1)) * FDIM;
        #pragma unroll
        for (int kc = 0; kc < 4; ++kc) {
          f32x4 a0 = *(const f32x4*)(nfr + kc * 32 + 8 * g);
          f32x4 a1 = *(const f32x4*)(nfr + kc * 32 + 8 * g + 4);
          float t[8];
          t[0]=a0[0]; t[1]=a0[1]; t[2]=a0[2]; t[3]=a0[3];
          t[4]=a1[0]; t[5]=a1[1]; t[6]=a1[2]; t[7]=a1[3];
          short8 o;
          #pragma unroll
          for (int i = 0; i < 8; ++i) o[i] = (short)f2b(t[i]);
          Bn[rg][kc] = o;
        }
      }
      f32x4 b0 = *(const f32x4*)(be + 16 * cc0 + 4 * g);
      f32x4 b1 = *(const f32x4*)(be + 16 * (cc0 + 1) + 4 * g);
      acc[0][0] = b0; acc[0][1] = b0; acc[1][0] = b1; acc[1][1] = b1;
      WAITVM(0);
      #pragma unroll
      for (int ct = 0; ct < 2; ++ct)
        #pragma unroll
        for (int rg = 0; rg < 2; ++rg)
          #pragma unroll
          for (int kc = 0; kc < 4; ++kc)
            acc[ct][rg] = mfma16(WE[ct * 4 + kc], Bn[rg][kc], acc[ct][rg]);
      #pragma unroll
      for (int ct = 0; ct < 2; ++ct)
        #pragma unroll
        for (int rg = 0; rg < 2; ++rg) {
          f32x4 o;
          o[0]=tanhf(acc[ct][rg][0]); o[1]=tanhf(acc[ct][rg][1]);
          o[2]=tanhf(acc[ct][rg][2]); o[3]=tanhf(acc[ct][rg][3]);
          st_lds8(Bs[3], rg * 16 + r, 32 * (cc0 + ct) + 8 * g, packu2(o));
        }
    }
    LBAR();

    // ---- S1..S8 (R17 body verbatim) ----
    ldw_asm(mpf + 65536, 4096, WB, cc0, lane);
    WAITVM(16);
    stage_mm(WA, Bs[0], bias_s, 0, acc, r, g, cc0);
    relu_acc(acc);
    wr_acc(Bs[1], acc, cc0, r, g);
    cp_acc(X, acc);
    LBAR();

    ldw_asm(mpf + 131072, 4096, WA, cc0, lane);
    WAITVM(16);
    stage_mm(WB, Bs[1], bias_s, 1, acc, r, g, cc0);
    relu_acc(acc);
    wr_acc_add(Bs[2], acc, X, cc0, r, g);
    cp_acc(X, acc);
    LBAR();

    ldw_asm(mpf + 196608, 4096, WB, cc0, lane);
    WAITVM(16);
    stage_mm(WA, Bs[2], bias_s, 2, acc, r, g, cc0);
    relu_acc(acc);
    wr_acc_add(Bs[0], acc, X, cc0, r, g);
    LBAR();

    ldw_asm(ne0f, 8192, WA, cc0, lane);
    WAITVM(16);
    stage_mm(WB, Bs[0], bias_s, 3, acc, r, g, cc0);
    relu_acc(acc);
    wr_acc(Bs[1], acc, cc0, r, g);
    LBAR();

    ldw_asm(ne0f + 4096, 8192, WB, cc0, lane);
    WAITVM(16);
    {
      acc[0][0] = *(const f32x4*)(bias_s + 4 * 256 + 16 * cc0 + 4 * g);
      acc[0][1] = acc[0][0];
      acc[1][0] = *(const f32x4*)(bias_s + 4 * 256 + 16 * (cc0 + 1) + 4 * g);
      acc[1][1] = acc[1][0];
      short8 B[2][4];
      rdBh(Bs[3], B, 0, r, g); mmhalf(WA, B, acc, 0);
      rdBh(Bs[3], B, 1, r, g); mmhalf(WA, B, acc, 1);
      WAITVM(0);
      rdBh(Bs[1], B, 0, r, g); mmhalf(WB, B, acc, 0);
      rdBh(Bs[1], B, 1, r, g); mmhalf(WB, B, acc, 1);
    }
    ldw_asm(nwf, 4096, WA, cc0, lane);
    relu_acc(acc);
    wr_acc(Bs[2], acc, cc0, r, g);
    cp_acc(X, acc);
    LBAR();

    ldw_asm(nwf + 65536, 4096, WB, cc0, lane);
    WAITVM(16);
    stage_mm(WA, Bs[2], bias_s, 5, acc, r, g, cc0);
    relu_acc(acc);
    wr_acc_add(Bs[0], acc, X, cc0, r, g);
    cp_acc(X, acc);
    LBAR();

    ldw_asm(nwf + 131072, 4096, WA, cc0, lane);
    WAITVM(16);
    stage_mm(WB, Bs[0], bias_s, 6, acc, r, g, cc0);
    relu_acc(acc);
    wr_acc_add(Bs[1], acc, X, cc0, r, g);
    LBAR();

    WAITVM(0);
    stage_mm(WA, Bs[1], bias_s, 7, acc, r, g, cc0);
    relu_acc(acc);
    #pragma unroll
    for (int rg = 0; rg < 2; ++rg) {
      int p = p0 + rg * 16 + r;
      if (p < PN) {
        float* og = eb + ((size_t)((l + 1) * PN) + p) * HDIM;
        *(f32x4*)(og + 16 * cc0 + 4 * g)       = acc[0][rg];
        *(f32x4*)(og + 16 * (cc0 + 1) + 4 * g) = acc[1][rg];
        ushort* oh = ebW + (size_t)p * HDIM;
        *(uint2*)(oh + 16 * cc0 + 4 * g)       = packu2(acc[0][rg]);
        *(uint2*)(oh + 16 * (cc0 + 1) + 4 * g) = packu2(acc[1][rg]);
      }
    }

    // ---- level boundary: device-scope visibility + grid barrier ----
    __threadfence();
    grid.sync();
  }
}

// ---------------- launch ----------------
extern "C" void kernel_launch(void* const* d_in, const int* in_sizes, int n_in,
                              void* d_out, int out_size, void* d_ws, size_t ws_size,
                              hipStream_t stream) {
  (void)in_sizes; (void)n_in; (void)out_size; (void)ws_size;
  const float* nf      = (const float*)d_in[0];
  const float* W_embed = (const float*)d_in[1];
  const float* b_embed = (const float*)d_in[2];
  const float* mp_w    = (const float*)d_in[3];
  const float* mp_b    = (const float*)d_in[4];
  const float* ne_w0   = (const float*)d_in[5];
  const float* ne_b0   = (const float*)d_in[6];
  const float* ne_w    = (const float*)d_in[7];
  const float* ne_b    = (const float*)d_in[8];
  const int*   esrc    = (const int*)d_in[9];
  const int*   edst    = (const int*)d_in[10];
  float* out = (float*)d_out;

  int*    counts  = (int*)d_ws;
  int*    buckets = (int*)((char*)d_ws + (512 << 10));
  ushort* wef     = (ushort*)((char*)d_ws + (13u << 20));
  ushort* mpf     = wef + 32768;
  ushort* ne0f    = mpf + 4 * 65536;
  ushort* nwf     = ne0f + 131072;
  ushort* eb16    = (ushort*)((char*)d_ws + (16u << 20));   // bf16 ring: 2 x PN x 256

  hipMemsetAsync(counts, 0, (NLVL - 1) * PN * sizeof(int), stream);
  fill_csr_kernel<<<((NLVL - 1) * EPLE + 255) / 256, 256, 0, stream>>>(esrc, edst, counts, buckets);
  prep_w<<<1024, 256, 0, stream>>>(W_embed, mp_w, ne_w0, ne_w, wef, mpf, ne0f, nwf);
  embed0<<<(PN + 15) / 16, 256, 0, stream>>>(nf, wef, b_embed, out, eb16);

  void* args[] = { (void*)&out, (void*)&nf, (void*)&eb16, (void*)&counts,
                   (void*)&buckets, (void*)&wef, (void*)&mpf, (void*)&ne0f,
                   (void*)&nwf, (void*)&b_embed, (void*)&mp_b, (void*)&ne_b0,
                   (void*)&ne_b };
  hipLaunchCooperativeKernel((const void*)level_persist, dim3(NBLK), dim3(512),
                             args, 0, stream);
}

// Round 19
// 736.957 us; speedup vs baseline: 2.5801x; 2.5801x over previous
//
#include <hip/hip_runtime.h>
#include <hip/hip_bf16.h>

#define NLVL 20
#define PN   5000
#define EPLE 40000
#define FDIM 128
#define HDIM 256
#define NTOT (NLVL * PN)
#define CAP  32
#define ROWS 32

#define STR_(x) #x
#define GLD(dst, ptr, IMM) \
  asm volatile("global_load_dwordx4 %0, %1, off offset:" STR_(IMM) : "=v"(dst) : "v"(ptr))
#define WAITVM(N) do { asm volatile("s_waitcnt vmcnt(" STR_(N) ")" ::: "memory"); \
                       __builtin_amdgcn_sched_barrier(0); } while (0)
#define LBAR() do { asm volatile("s_waitcnt lgkmcnt(0)\n\ts_barrier" ::: "memory"); \
                    __builtin_amdgcn_sched_barrier(0); } while (0)

typedef __attribute__((ext_vector_type(8))) short short8;
typedef __attribute__((ext_vector_type(4))) float f32x4;

__device__ __forceinline__ f32x4 mfma16(short8 a, short8 b, f32x4 c) {
  return __builtin_amdgcn_mfma_f32_16x16x32_bf16(a, b, c, 0, 0, 0);
}
__device__ __forceinline__ ushort f2b(float f) {
  union { float f; unsigned u; } v; v.f = f;
  unsigned r = v.u + 0x7FFFu + ((v.u >> 16) & 1u);   // RNE
  return (ushort)(r >> 16);
}
__device__ __forceinline__ uint2 packu2(f32x4 v) {
  union { uint2 u2; ushort s[4]; } p;
  p.s[0] = f2b(v[0]); p.s[1] = f2b(v[1]); p.s[2] = f2b(v[2]); p.s[3] = f2b(v[3]);
  return p.u2;
}
__device__ __forceinline__ void addbf4(f32x4& s, uint2 v) {
  s[0] += __uint_as_float(v.x << 16);
  s[1] += __uint_as_float(v.x & 0xFFFF0000u);
  s[2] += __uint_as_float(v.y << 16);
  s[3] += __uint_as_float(v.y & 0xFFFF0000u);
}
__device__ __forceinline__ f32x4 relu4(f32x4 a) {
  f32x4 o;
  o[0] = fmaxf(a[0], 0.f); o[1] = fmaxf(a[1], 0.f);
  o[2] = fmaxf(a[2], 0.f); o[3] = fmaxf(a[3], 0.f);
  return o;
}

// ---- LDS act buffers: [32 rows][256 cols] bf16, XOR-swizzled ----
__device__ __forceinline__ void st_lds8(ushort* buf, int row, int byteoff, uint2 v) {
  *(uint2*)((char*)buf + row * 512 + (byteoff ^ ((row & 7) << 4))) = v;
}
__device__ __forceinline__ short8 ld_lds16(const ushort* buf, int row, int byteoff) {
  return *(const short8*)((const char*)buf + row * 512 + (byteoff ^ ((row & 7) << 4)));
}

// ---- fragment-major weights: chunk(ct, kc) = 1KB of lane-ordered short8 ----
// K=256 matrices: ct stride 4096 ushorts; ne0 (K=512): 8192; embed (K=128): 2048.
__device__ __forceinline__ void ldw_asm(const ushort* __restrict__ Wm, int ctstride,
                                        short8* W, int cc0, int lane) {
  const ushort* pa = Wm + (size_t)cc0 * ctstride + lane * 8;
  const ushort* pb = pa + ctstride;
  GLD(W[0],  pa, 0);        GLD(W[1],  pa, 1024);
  GLD(W[2],  pa, 2048);     GLD(W[3],  pa, 3072);
  GLD(W[4],  pa + 2048, 0); GLD(W[5],  pa + 2048, 1024);
  GLD(W[6],  pa + 2048, 2048); GLD(W[7], pa + 2048, 3072);
  GLD(W[8],  pb, 0);        GLD(W[9],  pb, 1024);
  GLD(W[10], pb, 2048);     GLD(W[11], pb, 3072);
  GLD(W[12], pb + 2048, 0); GLD(W[13], pb + 2048, 1024);
  GLD(W[14], pb + 2048, 2048); GLD(W[15], pb + 2048, 3072);
}

__device__ __forceinline__ void rdBh(const ushort* buf, short8 B[2][4], int h, int r, int g) {
  #pragma unroll
  for (int rg = 0; rg < 2; ++rg)
    #pragma unroll
    for (int kc = 0; kc < 4; ++kc)
      B[rg][kc] = ld_lds16(buf, rg * 16 + r, 64 * (h * 4 + kc) + 16 * g);
}
__device__ __forceinline__ void mmhalf(const short8* W, short8 B[2][4],
                                       f32x4 acc[2][2], int h) {
  #pragma unroll
  for (int ct = 0; ct < 2; ++ct)
    #pragma unroll
    for (int rg = 0; rg < 2; ++rg)
      #pragma unroll
      for (int kc = 0; kc < 4; ++kc)
        acc[ct][rg] = mfma16(W[ct * 8 + h * 4 + kc], B[rg][kc], acc[ct][rg]);
}
__device__ __forceinline__ void stage_mm(const short8* W, const ushort* inbuf,
                                         const float* bias_s, int slot,
                                         f32x4 acc[2][2], int r, int g, int cc0) {
  #pragma unroll
  for (int ct = 0; ct < 2; ++ct) {
    f32x4 b = *(const f32x4*)(bias_s + slot * 256 + 16 * (cc0 + ct) + 4 * g);
    acc[ct][0] = b; acc[ct][1] = b;
  }
  short8 B[2][4];
  rdBh(inbuf, B, 0, r, g);
  mmhalf(W, B, acc, 0);
  rdBh(inbuf, B, 1, r, g);
  mmhalf(W, B, acc, 1);
}
__device__ __forceinline__ void relu_acc(f32x4 a[2][2]) {
  #pragma unroll
  for (int ct = 0; ct < 2; ++ct)
    #pragma unroll
    for (int rg = 0; rg < 2; ++rg) a[ct][rg] = relu4(a[ct][rg]);
}
__device__ __forceinline__ void wr_acc(ushort* buf, f32x4 a[2][2], int cc0, int r, int g) {
  #pragma unroll
  for (int ct = 0; ct < 2; ++ct)
    #pragma unroll
    for (int rg = 0; rg < 2; ++rg)
      st_lds8(buf, rg * 16 + r, 32 * (cc0 + ct) + 8 * g, packu2(a[ct][rg]));
}
__device__ __forceinline__ void wr_acc_add(ushort* buf, f32x4 a[2][2], f32x4 x[2][2],
                                           int cc0, int r, int g) {
  #pragma unroll
  for (int ct = 0; ct < 2; ++ct)
    #pragma unroll
    for (int rg = 0; rg < 2; ++rg)
      st_lds8(buf, rg * 16 + r, 32 * (cc0 + ct) + 8 * g, packu2(a[ct][rg] + x[ct][rg]));
}
__device__ __forceinline__ void cp_acc(f32x4 d[2][2], f32x4 s[2][2]) {
  #pragma unroll
  for (int ct = 0; ct < 2; ++ct)
    #pragma unroll
    for (int rg = 0; rg < 2; ++rg) d[ct][rg] = s[ct][rg];
}

// ---------------- CSR-lite build ----------------
__global__ void fill_csr_kernel(const int* __restrict__ esrc, const int* __restrict__ edst,
                                int* __restrict__ counts, int* __restrict__ buckets) {
  int e = blockIdx.x * 256 + threadIdx.x;
  if (e >= (NLVL - 1) * EPLE) return;
  int l = e / EPLE;
  int key = l * PN + edst[e];
  int pos = atomicAdd(&counts[key], 1);
  if (pos < CAP) buckets[(size_t)key * CAP + pos] = esrc[e];
}

// ------- weight prep: fp32 [K][N] row-major -> bf16 fragment-major chunks -------
__global__ void prep_w(const float* __restrict__ we, const float* __restrict__ mpw,
                       const float* __restrict__ nw0, const float* __restrict__ nww,
                       ushort* __restrict__ wef, ushort* __restrict__ mpf,
                       ushort* __restrict__ ne0f, ushort* __restrict__ nwf) {
  int i = blockIdx.x * 256 + threadIdx.x;
  if (i < 32768) {
    int e = i & 7, lane = (i >> 3) & 63, kc = (i >> 9) & 3, ct = i >> 11;
    int r = lane & 15, g = lane >> 4;
    int k = kc * 32 + 8 * g + e, n = 16 * ct + r;
    wef[i] = f2b(we[k * 256 + n]);
  }
  if (i < 4 * 65536) {
    int mi = i >> 16, o = i & 65535;
    int e = o & 7, lane = (o >> 3) & 63, kc = (o >> 9) & 7, ct = o >> 12;
    int r = lane & 15, g = lane >> 4;
    int k = kc * 32 + 8 * g + e, n = 16 * ct + r;
    mpf[i] = f2b(mpw[mi * 65536 + k * 256 + n]);
  }
  if (i < 131072) {
    int e = i & 7, lane = (i >> 3) & 63, kc = (i >> 9) & 15, ct = i >> 13;
    int r = lane & 15, g = lane >> 4;
    int k = kc * 32 + 8 * g + e, n = 16 * ct + r;
    ne0f[i] = f2b(nw0[k * 256 + n]);
  }
  if (i < 3 * 65536) {
    int mi = i >> 16, o = i & 65535;
    int e = o & 7, lane = (o >> 3) & 63, kc = (o >> 9) & 7, ct = o >> 12;
    int r = lane & 15, g = lane >> 4;
    int k = kc * 32 + 8 * g + e, n = 16 * ct + r;
    nwf[i] = f2b(nww[mi * 65536 + k * 256 + n]);
  }
}

// -------- embed for level-0 rows: 16 rows/block, 4 waves x 4 col-tiles --------
__global__ __launch_bounds__(256, 4) void embed0(
    const float* __restrict__ nf, const ushort* __restrict__ wef,
    const float* __restrict__ be, float* __restrict__ out,
    ushort* __restrict__ eb16) {
  const int w = threadIdx.x >> 6, lane = threadIdx.x & 63;
  const int r = lane & 15, g = lane >> 4;
  const int p = blockIdx.x * 16 + r;
  const int pc = p < PN ? p : PN - 1;

  short8 Bn[4];
  const float* nfr = nf + (size_t)pc * FDIM;
  #pragma unroll
  for (int kc = 0; kc < 4; ++kc) {
    f32x4 a0 = *(const f32x4*)(nfr + kc * 32 + 8 * g);
    f32x4 a1 = *(const f32x4*)(nfr + kc * 32 + 8 * g + 4);
    float t[8];
    t[0]=a0[0]; t[1]=a0[1]; t[2]=a0[2]; t[3]=a0[3];
    t[4]=a1[0]; t[5]=a1[1]; t[6]=a1[2]; t[7]=a1[3];
    short8 o;
    #pragma unroll
    for (int i = 0; i < 8; ++i) o[i] = (short)f2b(t[i]);
    Bn[kc] = o;
  }
  const int ct0 = 4 * w;
  #pragma unroll
  for (int t = 0; t < 4; ++t) {
    const int ct = ct0 + t;
    f32x4 acc = *(const f32x4*)(be + 16 * ct + 4 * g);
    #pragma unroll
    for (int kc = 0; kc < 4; ++kc)
      acc = mfma16(*(const short8*)(wef + (size_t)ct * 2048 + kc * 512 + lane * 8),
                   Bn[kc], acc);
    f32x4 o;
    o[0]=tanhf(acc[0]); o[1]=tanhf(acc[1]); o[2]=tanhf(acc[2]); o[3]=tanhf(acc[3]);
    if (p < PN) {
      *(f32x4*)(out + (size_t)p * HDIM + 16 * ct + 4 * g) = o;
      *(uint2*)(eb16 + (size_t)p * HDIM + 16 * ct + 4 * g) = packu2(o);
    }
  }
}

// ------- fused per-level chain: 32 rows/block, 8 waves x (2 ct x 2 rg) -------
// Best verified structure (R17): fragment-major weights (1KB burst loads),
// LDS-staged gather indices, named dual-buffer weight ring with counted vmcnt
// across LDS-only barriers, bf16 embed ring, 157 blocks = 1 block/CU.
__global__ __launch_bounds__(512, 2) void level_mfma(
    float* __restrict__ eb, const float* __restrict__ nf,
    const ushort* __restrict__ ebA, ushort* __restrict__ ebW,
    const int* __restrict__ counts, const int* __restrict__ buckets,
    const ushort* __restrict__ wef,
    const ushort* __restrict__ mpf, const ushort* __restrict__ ne0f,
    const ushort* __restrict__ nwf,
    const float* __restrict__ be, const float* __restrict__ mpb,
    const float* __restrict__ neb0, const float* __restrict__ neb, int l) {
  __shared__ ushort Bs[4][ROWS * 256];
  __shared__ float bias_s[8 * 256];
  __shared__ int idx_s[ROWS * CAP];      // 4KB: this block's bucket lists
  __shared__ int cnt_s[ROWS];
  const int tid = threadIdx.x, w = tid >> 6, lane = tid & 63;
  const int r = lane & 15, g = lane >> 4;
  const int p0 = blockIdx.x * ROWS;
  const int cc0 = 2 * w;
  const int lP = l * PN;

  short8 WA[16], WB[16], WE[8];
  f32x4 acc[2][2], X[2][2];

  // ---- stage bucket index table + counts (coalesced; no dependent chains) ----
  {
    const int* gsrc = buckets + (size_t)(lP + p0) * CAP;
    for (int i = tid; i < ROWS * CAP; i += 512) idx_s[i] = gsrc[i];
    if (tid < ROWS) {
      int p = p0 + tid;
      cnt_s[tid] = (p < PN) ? min(counts[lP + p], CAP) : 0;
    }
  }

  // ---- issue embed weights + S1 weights (land under phase-0 gather) ----
  {
    const ushort* pe0 = wef + (size_t)cc0 * 2048 + lane * 8;
    const ushort* pe1 = pe0 + 2048;
    GLD(WE[0], pe0, 0); GLD(WE[1], pe0, 1024); GLD(WE[2], pe0, 2048); GLD(WE[3], pe0, 3072);
    GLD(WE[4], pe1, 0); GLD(WE[5], pe1, 1024); GLD(WE[6], pe1, 2048); GLD(WE[7], pe1, 3072);
  }
  ldw_asm(mpf, 4096, WA, cc0, lane);                   // S1 weights

  // bias table -> LDS (slots: 0..3 mp_b, 4 ne_b0, 5..7 ne_b)
  for (int i = tid; i < 2048; i += 512) {
    float v;
    if (i < 1024) v = mpb[i];
    else if (i < 1280) v = neb0[i - 1024];
    else v = neb[i - 1280];
    bias_s[i] = v;
  }
  LBAR();   // idx_s/cnt_s staged by all waves; visible before gather reads

  // ---- phase 0: gather (4 rows/wave) via LDS indices -> Bs0 ----
  {
    const int qb = 4 * w;
    f32x4 s[4]; int cnt[4];
    #pragma unroll
    for (int i = 0; i < 4; ++i) {
      cnt[i] = cnt_s[qb + i];
      s[i][0]=0.f; s[i][1]=0.f; s[i][2]=0.f; s[i][3]=0.f;
    }
    int mx = max(max(cnt[0], cnt[1]), max(cnt[2], cnt[3]));
    for (int j = 0; j < mx; ++j) {
      #pragma unroll
      for (int i = 0; i < 4; ++i)
        if (j < cnt[i]) {
          int sl = idx_s[(qb + i) * CAP + j] - lP;
          addbf4(s[i], *(const uint2*)(ebA + (size_t)sl * HDIM + 4 * lane));
        }
    }
    #pragma unroll
    for (int i = 0; i < 4; ++i)
      st_lds8(Bs[0], qb + i, 8 * lane, packu2(s[i]));
  }

  // ---- fused embed: base = tanh(nf @ We + be) -> Bs3 ----
  {
    short8 Bn[2][4];
    #pragma unroll
    for (int rg = 0; rg < 2; ++rg) {
      int p = p0 + rg * 16 + r;
      const float* nfr = nf + (size_t)((l + 1) * PN + (p < PN ? p : PN - 1)) * FDIM;
      #pragma unroll
      for (int kc = 0; kc < 4; ++kc) {
        f32x4 a0 = *(const f32x4*)(nfr + kc * 32 + 8 * g);
        f32x4 a1 = *(const f32x4*)(nfr + kc * 32 + 8 * g + 4);
        float t[8];
        t[0]=a0[0]; t[1]=a0[1]; t[2]=a0[2]; t[3]=a0[3];
        t[4]=a1[0]; t[5]=a1[1]; t[6]=a1[2]; t[7]=a1[3];
        short8 o;
        #pragma unroll
        for (int i = 0; i < 8; ++i) o[i] = (short)f2b(t[i]);
        Bn[rg][kc] = o;
      }
    }
    f32x4 b0 = *(const f32x4*)(be + 16 * cc0 + 4 * g);
    f32x4 b1 = *(const f32x4*)(be + 16 * (cc0 + 1) + 4 * g);
    acc[0][0] = b0; acc[0][1] = b0; acc[1][0] = b1; acc[1][1] = b1;
    WAITVM(0);                                          // WE + all loads landed
    #pragma unroll
    for (int ct = 0; ct < 2; ++ct)
      #pragma unroll
      for (int rg = 0; rg < 2; ++rg)
        #pragma unroll
        for (int kc = 0; kc < 4; ++kc)
          acc[ct][rg] = mfma16(WE[ct * 4 + kc], Bn[rg][kc], acc[ct][rg]);
    #pragma unroll
    for (int ct = 0; ct < 2; ++ct)
      #pragma unroll
      for (int rg = 0; rg < 2; ++rg) {
        f32x4 o;
        o[0]=tanhf(acc[ct][rg][0]); o[1]=tanhf(acc[ct][rg][1]);
        o[2]=tanhf(acc[ct][rg][2]); o[3]=tanhf(acc[ct][rg][3]);
        st_lds8(Bs[3], rg * 16 + r, 32 * (cc0 + ct) + 8 * g, packu2(o));
      }
  }
  LBAR();

  // ---- S1: t0 ---- [use WA(mp0); issue WB=mp1]
  ldw_asm(mpf + 65536, 4096, WB, cc0, lane);
  WAITVM(16);
  stage_mm(WA, Bs[0], bias_s, 0, acc, r, g, cc0);
  relu_acc(acc);
  wr_acc(Bs[1], acc, cc0, r, g);
  cp_acc(X, acc);
  LBAR();

  // ---- S2: u1 ---- [use WB(mp1); issue WA=mp2]
  ldw_asm(mpf + 131072, 4096, WA, cc0, lane);
  WAITVM(16);
  stage_mm(WB, Bs[1], bias_s, 1, acc, r, g, cc0);
  relu_acc(acc);
  wr_acc_add(Bs[2], acc, X, cc0, r, g);                 // t0+u1
  cp_acc(X, acc);                                       // keep u1
  LBAR();

  // ---- S3: u2 ---- [use WA(mp2); issue WB=mp3]
  ldw_asm(mpf + 196608, 4096, WB, cc0, lane);
  WAITVM(16);
  stage_mm(WA, Bs[2], bias_s, 2, acc, r, g, cc0);
  relu_acc(acc);
  wr_acc_add(Bs[0], acc, X, cc0, r, g);                 // u1+u2
  LBAR();

  // ---- S4: mr ---- [use WB(mp3); issue WA=ne0 h1 (kc 0..7)]
  ldw_asm(ne0f, 8192, WA, cc0, lane);
  WAITVM(16);
  stage_mm(WB, Bs[0], bias_s, 3, acc, r, g, cc0);
  relu_acc(acc);
  wr_acc(Bs[1], acc, cc0, r, g);                        // mr
  LBAR();

  // ---- S5: x0 = relu([base|mr] @ ne_w0) ---- [h1 in WA; issue h2 -> WB]
  ldw_asm(ne0f + 4096, 8192, WB, cc0, lane);            // h2 (kc 8..15)
  WAITVM(16);                                           // h1 landed
  {
    acc[0][0] = *(const f32x4*)(bias_s + 4 * 256 + 16 * cc0 + 4 * g);
    acc[0][1] = acc[0][0];
    acc[1][0] = *(const f32x4*)(bias_s + 4 * 256 + 16 * (cc0 + 1) + 4 * g);
    acc[1][1] = acc[1][0];
    short8 B[2][4];
    rdBh(Bs[3], B, 0, r, g); mmhalf(WA, B, acc, 0);     // base k 0..127
    rdBh(Bs[3], B, 1, r, g); mmhalf(WA, B, acc, 1);     // base k 128..255
    WAITVM(0);                                          // h2 landed
    rdBh(Bs[1], B, 0, r, g); mmhalf(WB, B, acc, 0);     // mr k 0..127
    rdBh(Bs[1], B, 1, r, g); mmhalf(WB, B, acc, 1);     // mr k 128..255
  }
  ldw_asm(nwf, 4096, WA, cc0, lane);                    // issue S6 (h1 dead)
  relu_acc(acc);
  wr_acc(Bs[2], acc, cc0, r, g);                        // x0
  cp_acc(X, acc);                                       // keep x0
  LBAR();

  // ---- S6: v1 ---- [use WA(nw0); issue WB=nw1]
  ldw_asm(nwf + 65536, 4096, WB, cc0, lane);
  WAITVM(16);
  stage_mm(WA, Bs[2], bias_s, 5, acc, r, g, cc0);
  relu_acc(acc);
  wr_acc_add(Bs[0], acc, X, cc0, r, g);                 // x0+v1
  cp_acc(X, acc);                                       // keep v1
  LBAR();

  // ---- S7: v2 ---- [use WB(nw1); issue WA=nw2]
  ldw_asm(nwf + 131072, 4096, WA, cc0, lane);
  WAITVM(16);
  stage_mm(WB, Bs[0], bias_s, 6, acc, r, g, cc0);
  relu_acc(acc);
  wr_acc_add(Bs[1], acc, X, cc0, r, g);                 // v1+v2
  LBAR();

  // ---- S8: out ---- [use WA(nw2)]
  WAITVM(0);
  stage_mm(WA, Bs[1], bias_s, 7, acc, r, g, cc0);
  relu_acc(acc);
  #pragma unroll
  for (int rg = 0; rg < 2; ++rg) {
    int p = p0 + rg * 16 + r;
    if (p < PN) {
      float* og = eb + ((size_t)((l + 1) * PN) + p) * HDIM;
      *(f32x4*)(og + 16 * cc0 + 4 * g)       = acc[0][rg];
      *(f32x4*)(og + 16 * (cc0 + 1) + 4 * g) = acc[1][rg];
      ushort* oh = ebW + (size_t)p * HDIM;
      *(uint2*)(oh + 16 * cc0 + 4 * g)       = packu2(acc[0][rg]);
      *(uint2*)(oh + 16 * (cc0 + 1) + 4 * g) = packu2(acc[1][rg]);
    }
  }
}

// ---------------- launch ----------------
extern "C" void kernel_launch(void* const* d_in, const int* in_sizes, int n_in,
                              void* d_out, int out_size, void* d_ws, size_t ws_size,
                              hipStream_t stream) {
  (void)in_sizes; (void)n_in; (void)out_size; (void)ws_size;
  const float* nf      = (const float*)d_in[0];
  const float* W_embed = (const float*)d_in[1];
  const float* b_embed = (const float*)d_in[2];
  const float* mp_w    = (const float*)d_in[3];
  const float* mp_b    = (const float*)d_in[4];
  const float* ne_w0   = (const float*)d_in[5];
  const float* ne_b0   = (const float*)d_in[6];
  const float* ne_w    = (const float*)d_in[7];
  const float* ne_b    = (const float*)d_in[8];
  const int*   esrc    = (const int*)d_in[9];
  const int*   edst    = (const int*)d_in[10];
  float* out = (float*)d_out;

  int*    counts  = (int*)d_ws;
  int*    buckets = (int*)((char*)d_ws + (512 << 10));
  ushort* wef     = (ushort*)((char*)d_ws + (13u << 20));   // fragment-major weights
  ushort* mpf     = wef + 32768;
  ushort* ne0f    = mpf + 4 * 65536;
  ushort* nwf     = ne0f + 131072;
  ushort* eb16    = (ushort*)((char*)d_ws + (16u << 20));   // bf16 ring: 2 x PN x 256

  hipMemsetAsync(counts, 0, (NLVL - 1) * PN * sizeof(int), stream);
  fill_csr_kernel<<<((NLVL - 1) * EPLE + 255) / 256, 256, 0, stream>>>(esrc, edst, counts, buckets);
  prep_w<<<1024, 256, 0, stream>>>(W_embed, mp_w, ne_w0, ne_w, wef, mpf, ne0f, nwf);
  embed0<<<(PN + 15) / 16, 256, 0, stream>>>(nf, wef, b_embed, out, eb16);
  for (int l = 0; l < NLVL - 1; ++l) {
    ushort* ebA = eb16 + (size_t)(l & 1) * PN * HDIM;
    ushort* ebW = eb16 + (size_t)((l + 1) & 1) * PN * HDIM;
    level_mfma<<<(PN + ROWS - 1) / ROWS, 512, 0, stream>>>(out, nf, ebA, ebW,
                                                           counts, buckets,
                                                           wef, mpf, ne0f, nwf,
                                                           b_embed, mp_b, ne_b0, ne_b, l);
  }
}